// Round 10
// baseline (893.245 us; speedup 1.0000x reference)
//
#include <hip/hip_runtime.h>

// ODEBlock1D RK4, B=32 L=8192 C=64. R10: R7 chassis (best measured, 685us)
// with 4 MFMA bands/wave: CROWS 96->128, TILE 80->112, NBLK 103->74.
// Work per barrier interval +33%, block-rounds -28%, halo redundancy
// 1.20->1.14. R9's lambda alias-unswitch reverted (measured -13%).
// 4 launches, 2 RK4 steps each, halo 8; yR in regs; cvt_pk; (256,3).

#define BB 32
#define LL 8192
#define CC 64
#define HALO 8           // 8 evals x 1 conv-halo row per eval, each side
#define TILE 112         // central rows stored per block (CROWS - 2*HALO)
#define NBLK 74          // ceil(8192/112)
#define CROWS 128        // compute rows (8 MFMA bands, 4 per wave-row-half)
#define BUFR 130         // + 2 conv-pad rows (z row = r+1)
#define ZST 72           // shorts per z row (144 B, 16B-aligned rows)
#define THREADS 256

typedef __attribute__((ext_vector_type(8))) short bf16x8;
typedef __attribute__((ext_vector_type(4))) float f32x4;

__device__ __forceinline__ unsigned bf_rne(float f) {
    unsigned u = __float_as_uint(f);
    return u + 0x7fffu + ((u >> 16) & 1u);   // bf16 RNE in high 16 bits
}
__device__ __forceinline__ short bf16_of(float f) { return (short)(bf_rne(f) >> 16); }
__device__ __forceinline__ unsigned cvtpk(float lo, float hi) {
    // low16 = bf16_rne(lo), high16 = bf16_rne(hi) in one VALU op
    unsigned r;
    asm("v_cvt_pk_bf16_f32 %0, %1, %2" : "=v"(r) : "v"(lo), "v"(hi));
    return r;
}

__launch_bounds__(THREADS, 3)
__global__ void step_kernel(const float* __restrict__ y_in, float* __restrict__ y_out,
                            const float* __restrict__ w, const float* __restrict__ bias,
                            float t0, float h)
{
    __shared__ unsigned short zA[BUFR * ZST];   // 18720 B
    __shared__ unsigned short zB[BUFR * ZST];   // 18720 B  (total 37440 B)

    const int tid = threadIdx.x;
    const int b = blockIdx.y;
    const int l0 = blockIdx.x * TILE;
    const int lane = tid & 63;
    const int wv = tid >> 6;
    const int ch = wv & 1;             // co half: co in [ch*32, ch*32+32)
    const int rh = wv >> 1;            // row half: bands rh*4 .. rh*4+3
    const int g = lane >> 4;
    const int ml = lane & 15;
    const int co = ch * 32 + 2 * ml;   // lane's adjacent co pair
    const bool edge = (blockIdx.x == 0) || (blockIdx.x == NBLK - 1);

    // valid row range: r in [rmin, rmax) <-> l in [0, LL)
    const int rmin = (blockIdx.x == 0) ? HALO : 0;
    const int rmax = min(CROWS, LL - l0 + HALO);

    // zero conv-pad rows (z rows 0 and BUFR-1) of both buffers
    if (tid < 64) {
        zA[tid] = 0; zA[(BUFR - 1) * ZST + tid] = 0;
        zB[tid] = 0; zB[(BUFR - 1) * ZST + tid] = 0;
    }

    // ---- B fragments (bf16 RNE): chunk c: kw=c>>1, ci=(c&1)*32 + g*8 + j ----
    bf16x8 Bf[6][2];
#pragma unroll
    for (int c = 0; c < 6; c++) {
        const float* wp = w + (c >> 1) * (65 * CC) + (((c & 1) * 32) + g * 8) * CC + co;
#pragma unroll
        for (int j = 0; j < 8; j++) {
            float2 v = *(const float2*)(wp + j * CC);
            Bf[c][0][j] = bf16_of(v.x);
            Bf[c][1][j] = bf16_of(v.y);
        }
    }
    const float2 wt0 = *(const float2*)(w + 0 * (65 * CC) + CC * CC + co);
    const float2 wt1 = *(const float2*)(w + 1 * (65 * CC) + CC * CC + co);
    const float2 wt2 = *(const float2*)(w + 2 * (65 * CC) + CC * CC + co);
    const float2 bv  = *(const float2*)(bias + co);

    // ---- stage: z0 = bf16(y) -> zA; coalesced float4 ----
    const float* yrow = y_in + ((size_t)b * LL + (size_t)(l0 - HALO)) * CC;
    for (int idx = tid; idx < CROWS * 16; idx += THREADS) {
        const int row = idx >> 4;
        const int c4 = (idx & 15) * 4;
        float4 v = make_float4(0.f, 0.f, 0.f, 0.f);
        if (row >= rmin && row < rmax)
            v = *(const float4*)(yrow + (size_t)row * CC + c4);
        uint2 p;
        p.x = cvtpk(v.x, v.y);
        p.y = cvtpk(v.z, v.w);
        *(uint2*)&zA[(row + 1) * ZST + c4] = p;
    }

    // ---- y base into registers at this lane's output positions (fp32) ----
    float2 yR[4][4];
#pragma unroll
    for (int bb = 0; bb < 4; bb++) {
#pragma unroll
        for (int i = 0; i < 4; i++) {
            const int r = (rh * 4 + bb) * 16 + g * 4 + i;
            float2 v = make_float2(0.f, 0.f);
            if (r >= rmin && r < rmax)
                v = *(const float2*)(y_in + ((size_t)b * LL + (size_t)(l0 - HALO + r)) * CC + co);
            yR[bb][i] = v;
        }
    }
    __syncthreads();

    float2 aR[4][4];
    const float ca[4]  = {h / 6.f, h / 3.f, h / 3.f, h / 6.f};
    const float cuv[4] = {0.5f * h, 0.5f * h, h, 0.f};
    const float tof[4] = {0.f, 0.5f * h, 0.5f * h, h};

#pragma unroll 1
    for (int e4 = 0; e4 < 8; e4++) {
        const int e = e4 & 3;
        const unsigned short* zin = (e4 & 1) ? zB : zA;
        unsigned short* zout = (e4 & 1) ? zA : zB;
        const float t = t0 + ((e4 >> 2) ? h : 0.f) + tof[e];
        const float cacc = ca[e], cuu = cuv[e];
        const float tbx = t * (wt0.x + wt1.x + wt2.x) + bv.x;
        const float tby = t * (wt0.y + wt1.y + wt2.y) + bv.y;

#pragma unroll
        for (int bb = 0; bb < 4; bb++) {
            const int r0 = (rh * 4 + bb) * 16;
            f32x4 acc0 = {0.f, 0.f, 0.f, 0.f};
            f32x4 acc1 = {0.f, 0.f, 0.f, 0.f};
#pragma unroll
            for (int c = 0; c < 6; c++) {
                const int zr = r0 + ml + (c >> 1);   // data row r0+ml-1+kw -> z row +1
                const bf16x8 a =
                    *(const bf16x8*)&zin[zr * ZST + ((c & 1) * 32) + g * 8];
                acc0 = __builtin_amdgcn_mfma_f32_16x16x32_bf16(a, Bf[c][0], acc0, 0, 0, 0);
                acc1 = __builtin_amdgcn_mfma_f32_16x16x32_bf16(a, Bf[c][1], acc1, 0, 0, 0);
            }
#pragma unroll
            for (int i = 0; i < 4; i++) {
                const int r = r0 + g * 4 + i;
                float k0 = acc0[i] + tbx;
                float k1 = acc1[i] + tby;
                if (edge) {
                    const int l = l0 - HALO + r;
                    if (l == 0)      { k0 -= t * wt0.x; k1 -= t * wt0.y; }
                    if (l == LL - 1) { k0 -= t * wt2.x; k1 -= t * wt2.y; }
                }
                k0 = fmaxf(k0, 0.f);
                k1 = fmaxf(k1, 0.f);
                const float2 y2 = yR[bb][i];
                if (e == 0) {
                    aR[bb][i].x = y2.x + cacc * k0;
                    aR[bb][i].y = y2.y + cacc * k1;
                } else {
                    aR[bb][i].x += cacc * k0;
                    aR[bb][i].y += cacc * k1;
                }
                if (e4 == 3)   // step-1 done: new y base = aR, stays in regs
                    yR[bb][i] = aR[bb][i];
                if (e4 != 7) {
                    float u0 = 0.f, u1 = 0.f;
                    if (r >= rmin && r < rmax) {     // seq-boundary rows stay 0
                        if (e == 3) { u0 = yR[bb][i].x; u1 = yR[bb][i].y; }
                        else        { u0 = y2.x + cuu * k0; u1 = y2.y + cuu * k1; }
                    }
                    *(unsigned*)&zout[(r + 1) * ZST + co] = cvtpk(u0, u1);
                }
            }
        }
        if (e4 != 7) __syncthreads();
    }

    // ---- store central rows (r in [HALO, HALO+TILE) and < rmax) ----
#pragma unroll
    for (int bb = 0; bb < 4; bb++) {
        const int r0 = (rh * 4 + bb) * 16;
#pragma unroll
        for (int i = 0; i < 4; i++) {
            const int r = r0 + g * 4 + i;
            if (r >= HALO && r < HALO + TILE && r < rmax) {
                const int l = l0 - HALO + r;
                *(float2*)(y_out + ((size_t)b * LL + l) * CC + co) = aR[bb][i];
            }
        }
    }
}

extern "C" void kernel_launch(void* const* d_in, const int* in_sizes, int n_in,
                              void* d_out, int out_size, void* d_ws, size_t ws_size,
                              hipStream_t stream) {
    const float* x = (const float*)d_in[0];
    const float* w = (const float*)d_in[1];
    const float* bias = (const float*)d_in[2];
    float* out = (float*)d_out;
    float* P0 = (float*)d_ws;   // 32*8192*64*4 = 67.1 MB scratch
    const float h = 1.0f / 8.0f;

    dim3 grid(NBLK, BB), block(THREADS);
    for (int s = 0; s < 4; s++) {   // each kernel = 2 fused RK4 steps
        const float* yin = (s == 0) ? x : ((s & 1) ? P0 : out);
        float* yout = (s & 1) ? out : P0;   // s=3 (odd) writes `out`
        step_kernel<<<grid, block, 0, stream>>>(yin, yout, w, bias, (2 * s) * h, h);
    }
}

// Round 11
// 694.630 us; speedup vs baseline: 1.2859x; 1.2859x over previous
//
#include <hip/hip_runtime.h>

// ODEBlock1D RK4, B=32 L=8192 C=64. R11: 2-wave blocks (co-split only).
// R7's 4-wave block is lockstep-barrier-bound (85% stall; occupancy 2->4
// blocks/CU made no difference, issue cuts made no difference). Shrink the
// sync domain: each block = 2 waves (co halves) x 48 rows (3 bands),
// TILE=32, NBLK=256. Per-wave profile identical to R7 (84 VGPR, no spill);
// barriers sync 2 waves; 8 blocks/CU resident (LDS 14.4KB) de-phase freely.
// Redundancy 1.5x (MFMA floor still 6x below measured). 4 launches, 2 steps.

#define BB 32
#define LL 8192
#define CC 64
#define HALO 8           // 8 evals x 1 conv-halo row per eval, each side
#define TILE 32          // central rows stored per block (CROWS - 2*HALO)
#define NBLK 256         // 8192/32
#define CROWS 48         // compute rows (3 MFMA bands per wave)
#define BUFR 50          // + 2 conv-pad rows (z row = r+1)
#define ZST 72           // shorts per z row (144 B, 16B-aligned rows)
#define THREADS 128

typedef __attribute__((ext_vector_type(8))) short bf16x8;
typedef __attribute__((ext_vector_type(4))) float f32x4;

__device__ __forceinline__ unsigned bf_rne(float f) {
    unsigned u = __float_as_uint(f);
    return u + 0x7fffu + ((u >> 16) & 1u);   // bf16 RNE in high 16 bits
}
__device__ __forceinline__ short bf16_of(float f) { return (short)(bf_rne(f) >> 16); }
__device__ __forceinline__ unsigned cvtpk(float lo, float hi) {
    // low16 = bf16_rne(lo), high16 = bf16_rne(hi) in one VALU op
    unsigned r;
    asm("v_cvt_pk_bf16_f32 %0, %1, %2" : "=v"(r) : "v"(lo), "v"(hi));
    return r;
}

__launch_bounds__(THREADS, 3)
__global__ void step_kernel(const float* __restrict__ y_in, float* __restrict__ y_out,
                            const float* __restrict__ w, const float* __restrict__ bias,
                            float t0, float h)
{
    __shared__ unsigned short zA[BUFR * ZST];   // 7200 B
    __shared__ unsigned short zB[BUFR * ZST];   // 7200 B  (total 14400 B)

    const int tid = threadIdx.x;
    const int b = blockIdx.y;
    const int l0 = blockIdx.x * TILE;
    const int lane = tid & 63;
    const int ch = tid >> 6;           // co half: co in [ch*32, ch*32+32)
    const int g = lane >> 4;
    const int ml = lane & 15;
    const int co = ch * 32 + 2 * ml;   // lane's adjacent co pair
    const bool edge = (blockIdx.x == 0) || (blockIdx.x == NBLK - 1);

    // valid row range: r in [rmin, rmax) <-> l in [0, LL)
    const int rmin = (blockIdx.x == 0) ? HALO : 0;
    const int rmax = min(CROWS, LL - l0 + HALO);

    // zero conv-pad rows (z rows 0 and BUFR-1) of both buffers
    if (tid < 64) {
        zA[tid] = 0; zA[(BUFR - 1) * ZST + tid] = 0;
        zB[tid] = 0; zB[(BUFR - 1) * ZST + tid] = 0;
    }

    // ---- B fragments (bf16 RNE): chunk c: kw=c>>1, ci=(c&1)*32 + g*8 + j ----
    bf16x8 Bf[6][2];
#pragma unroll
    for (int c = 0; c < 6; c++) {
        const float* wp = w + (c >> 1) * (65 * CC) + (((c & 1) * 32) + g * 8) * CC + co;
#pragma unroll
        for (int j = 0; j < 8; j++) {
            float2 v = *(const float2*)(wp + j * CC);
            Bf[c][0][j] = bf16_of(v.x);
            Bf[c][1][j] = bf16_of(v.y);
        }
    }
    const float2 wt0 = *(const float2*)(w + 0 * (65 * CC) + CC * CC + co);
    const float2 wt1 = *(const float2*)(w + 1 * (65 * CC) + CC * CC + co);
    const float2 wt2 = *(const float2*)(w + 2 * (65 * CC) + CC * CC + co);
    const float2 bv  = *(const float2*)(bias + co);

    // ---- stage: z0 = bf16(y) -> zA; coalesced float4 ----
    const float* yrow = y_in + ((size_t)b * LL + (size_t)(l0 - HALO)) * CC;
    for (int idx = tid; idx < CROWS * 16; idx += THREADS) {
        const int row = idx >> 4;
        const int c4 = (idx & 15) * 4;
        float4 v = make_float4(0.f, 0.f, 0.f, 0.f);
        if (row >= rmin && row < rmax)
            v = *(const float4*)(yrow + (size_t)row * CC + c4);
        uint2 p;
        p.x = cvtpk(v.x, v.y);
        p.y = cvtpk(v.z, v.w);
        *(uint2*)&zA[(row + 1) * ZST + c4] = p;
    }

    // ---- y base into registers at this lane's output positions (fp32) ----
    float2 yR[3][4];
#pragma unroll
    for (int bb = 0; bb < 3; bb++) {
#pragma unroll
        for (int i = 0; i < 4; i++) {
            const int r = bb * 16 + g * 4 + i;
            float2 v = make_float2(0.f, 0.f);
            if (r >= rmin && r < rmax)
                v = *(const float2*)(y_in + ((size_t)b * LL + (size_t)(l0 - HALO + r)) * CC + co);
            yR[bb][i] = v;
        }
    }
    __syncthreads();

    float2 aR[3][4];
    const float ca[4]  = {h / 6.f, h / 3.f, h / 3.f, h / 6.f};
    const float cuv[4] = {0.5f * h, 0.5f * h, h, 0.f};
    const float tof[4] = {0.f, 0.5f * h, 0.5f * h, h};

#pragma unroll 1
    for (int e4 = 0; e4 < 8; e4++) {
        const int e = e4 & 3;
        const unsigned short* zin = (e4 & 1) ? zB : zA;
        unsigned short* zout = (e4 & 1) ? zA : zB;
        const float t = t0 + ((e4 >> 2) ? h : 0.f) + tof[e];
        const float cacc = ca[e], cuu = cuv[e];
        const float tbx = t * (wt0.x + wt1.x + wt2.x) + bv.x;
        const float tby = t * (wt0.y + wt1.y + wt2.y) + bv.y;

#pragma unroll
        for (int bb = 0; bb < 3; bb++) {
            const int r0 = bb * 16;
            f32x4 acc0 = {0.f, 0.f, 0.f, 0.f};
            f32x4 acc1 = {0.f, 0.f, 0.f, 0.f};
#pragma unroll
            for (int c = 0; c < 6; c++) {
                const int zr = r0 + ml + (c >> 1);   // data row r0+ml-1+kw -> z row +1
                const bf16x8 a =
                    *(const bf16x8*)&zin[zr * ZST + ((c & 1) * 32) + g * 8];
                acc0 = __builtin_amdgcn_mfma_f32_16x16x32_bf16(a, Bf[c][0], acc0, 0, 0, 0);
                acc1 = __builtin_amdgcn_mfma_f32_16x16x32_bf16(a, Bf[c][1], acc1, 0, 0, 0);
            }
#pragma unroll
            for (int i = 0; i < 4; i++) {
                const int r = r0 + g * 4 + i;
                float k0 = acc0[i] + tbx;
                float k1 = acc1[i] + tby;
                if (edge) {
                    const int l = l0 - HALO + r;
                    if (l == 0)      { k0 -= t * wt0.x; k1 -= t * wt0.y; }
                    if (l == LL - 1) { k0 -= t * wt2.x; k1 -= t * wt2.y; }
                }
                k0 = fmaxf(k0, 0.f);
                k1 = fmaxf(k1, 0.f);
                const float2 y2 = yR[bb][i];
                if (e == 0) {
                    aR[bb][i].x = y2.x + cacc * k0;
                    aR[bb][i].y = y2.y + cacc * k1;
                } else {
                    aR[bb][i].x += cacc * k0;
                    aR[bb][i].y += cacc * k1;
                }
                if (e4 == 3)   // step-1 done: new y base = aR, stays in regs
                    yR[bb][i] = aR[bb][i];
                if (e4 != 7) {
                    float u0 = 0.f, u1 = 0.f;
                    if (r >= rmin && r < rmax) {     // seq-boundary rows stay 0
                        if (e == 3) { u0 = yR[bb][i].x; u1 = yR[bb][i].y; }
                        else        { u0 = y2.x + cuu * k0; u1 = y2.y + cuu * k1; }
                    }
                    *(unsigned*)&zout[(r + 1) * ZST + co] = cvtpk(u0, u1);
                }
            }
        }
        if (e4 != 7) __syncthreads();
    }

    // ---- store central rows (r in [HALO, HALO+TILE) and < rmax) ----
#pragma unroll
    for (int bb = 0; bb < 3; bb++) {
        const int r0 = bb * 16;
#pragma unroll
        for (int i = 0; i < 4; i++) {
            const int r = r0 + g * 4 + i;
            if (r >= HALO && r < HALO + TILE && r < rmax) {
                const int l = l0 - HALO + r;
                *(float2*)(y_out + ((size_t)b * LL + l) * CC + co) = aR[bb][i];
            }
        }
    }
}

extern "C" void kernel_launch(void* const* d_in, const int* in_sizes, int n_in,
                              void* d_out, int out_size, void* d_ws, size_t ws_size,
                              hipStream_t stream) {
    const float* x = (const float*)d_in[0];
    const float* w = (const float*)d_in[1];
    const float* bias = (const float*)d_in[2];
    float* out = (float*)d_out;
    float* P0 = (float*)d_ws;   // 32*8192*64*4 = 67.1 MB scratch
    const float h = 1.0f / 8.0f;

    dim3 grid(NBLK, BB), block(THREADS);
    for (int s = 0; s < 4; s++) {   // each kernel = 2 fused RK4 steps
        const float* yin = (s == 0) ? x : ((s & 1) ? P0 : out);
        float* yout = (s & 1) ? out : P0;   // s=3 (odd) writes `out`
        step_kernel<<<grid, block, 0, stream>>>(yin, yout, w, bias, (2 * s) * h, h);
    }
}

// Round 12
// 674.784 us; speedup vs baseline: 1.3237x; 1.0294x over previous
//
#include <hip/hip_runtime.h>

// ODEBlock1D RK4, B=32 L=8192 C=64. R12: R7 chassis (best measured, 685us;
// fuse-2 + yR-in-regs + cvt_pk, (256,3)) + scratch-kill: the RK4 coefficient
// arrays ca[4]/cuv[4]/tof[4] were indexed by the RUNTIME loop var e ->
// per-thread scratch (rule #20), explaining the ~55-97MB/dispatch WRITE
// amplification seen in every round. Replaced by wave-uniform branchless
// selects (s_cselect, bit-identical values). Nothing else changed.

#define BB 32
#define LL 8192
#define CC 64
#define HALO 8           // 8 evals x 1 conv-halo row per eval, each side
#define TILE 80          // central rows stored per block (CROWS - 2*HALO)
#define NBLK 103         // ceil(8192/80)
#define CROWS 96         // compute rows (6 MFMA bands), r -> l = l0-HALO+r
#define BUFR 98          // + 2 conv-pad rows (z row = r+1)
#define ZST 72           // shorts per z row (144 B, 16B-aligned rows)
#define THREADS 256

typedef __attribute__((ext_vector_type(8))) short bf16x8;
typedef __attribute__((ext_vector_type(4))) float f32x4;

__device__ __forceinline__ unsigned bf_rne(float f) {
    unsigned u = __float_as_uint(f);
    return u + 0x7fffu + ((u >> 16) & 1u);   // bf16 RNE in high 16 bits
}
__device__ __forceinline__ short bf16_of(float f) { return (short)(bf_rne(f) >> 16); }
__device__ __forceinline__ unsigned cvtpk(float lo, float hi) {
    // low16 = bf16_rne(lo), high16 = bf16_rne(hi) in one VALU op
    unsigned r;
    asm("v_cvt_pk_bf16_f32 %0, %1, %2" : "=v"(r) : "v"(lo), "v"(hi));
    return r;
}

__launch_bounds__(THREADS, 3)
__global__ void step_kernel(const float* __restrict__ y_in, float* __restrict__ y_out,
                            const float* __restrict__ w, const float* __restrict__ bias,
                            float t0, float h)
{
    __shared__ unsigned short zA[BUFR * ZST];   // 14112 B
    __shared__ unsigned short zB[BUFR * ZST];   // 14112 B  (total 28224 B)

    const int tid = threadIdx.x;
    const int b = blockIdx.y;
    const int l0 = blockIdx.x * TILE;
    const int lane = tid & 63;
    const int wv = tid >> 6;
    const int ch = wv & 1;             // co half: co in [ch*32, ch*32+32)
    const int rh = wv >> 1;            // row half: bands rh*3 .. rh*3+2
    const int g = lane >> 4;
    const int ml = lane & 15;
    const int co = ch * 32 + 2 * ml;   // lane's adjacent co pair
    const bool edge = (blockIdx.x == 0) || (blockIdx.x == NBLK - 1);

    // valid row range: r in [rmin, rmax) <-> l in [0, LL)
    const int rmin = (blockIdx.x == 0) ? HALO : 0;
    const int rmax = min(CROWS, LL - l0 + HALO);

    // zero conv-pad rows (z rows 0 and BUFR-1) of both buffers
    if (tid < 64) {
        zA[tid] = 0; zA[(BUFR - 1) * ZST + tid] = 0;
        zB[tid] = 0; zB[(BUFR - 1) * ZST + tid] = 0;
    }

    // ---- B fragments (bf16 RNE): chunk c: kw=c>>1, ci=(c&1)*32 + g*8 + j ----
    bf16x8 Bf[6][2];
#pragma unroll
    for (int c = 0; c < 6; c++) {
        const float* wp = w + (c >> 1) * (65 * CC) + (((c & 1) * 32) + g * 8) * CC + co;
#pragma unroll
        for (int j = 0; j < 8; j++) {
            float2 v = *(const float2*)(wp + j * CC);
            Bf[c][0][j] = bf16_of(v.x);
            Bf[c][1][j] = bf16_of(v.y);
        }
    }
    const float2 wt0 = *(const float2*)(w + 0 * (65 * CC) + CC * CC + co);
    const float2 wt1 = *(const float2*)(w + 1 * (65 * CC) + CC * CC + co);
    const float2 wt2 = *(const float2*)(w + 2 * (65 * CC) + CC * CC + co);
    const float2 bv  = *(const float2*)(bias + co);

    // ---- stage: z0 = bf16(y) -> zA; coalesced float4 ----
    const float* yrow = y_in + ((size_t)b * LL + (size_t)(l0 - HALO)) * CC;
    for (int idx = tid; idx < CROWS * 16; idx += THREADS) {
        const int row = idx >> 4;
        const int c4 = (idx & 15) * 4;
        float4 v = make_float4(0.f, 0.f, 0.f, 0.f);
        if (row >= rmin && row < rmax)
            v = *(const float4*)(yrow + (size_t)row * CC + c4);
        uint2 p;
        p.x = cvtpk(v.x, v.y);
        p.y = cvtpk(v.z, v.w);
        *(uint2*)&zA[(row + 1) * ZST + c4] = p;
    }

    // ---- y base into registers at this lane's output positions (fp32) ----
    float2 yR[3][4];
#pragma unroll
    for (int bb = 0; bb < 3; bb++) {
#pragma unroll
        for (int i = 0; i < 4; i++) {
            const int r = (rh * 3 + bb) * 16 + g * 4 + i;
            float2 v = make_float2(0.f, 0.f);
            if (r >= rmin && r < rmax)
                v = *(const float2*)(y_in + ((size_t)b * LL + (size_t)(l0 - HALO + r)) * CC + co);
            yR[bb][i] = v;
        }
    }
    __syncthreads();

    float2 aR[3][4];

#pragma unroll 1
    for (int e4 = 0; e4 < 8; e4++) {
        const int e = e4 & 3;
        const unsigned short* zin = (e4 & 1) ? zB : zA;
        unsigned short* zout = (e4 & 1) ? zA : zB;
        // RK4 coefficients via wave-uniform selects (NO runtime-indexed
        // arrays -> no scratch). Values bit-identical to the old tables.
        const float cacc = (e == 1 || e == 2) ? (h / 3.f) : (h / 6.f);
        const float cuu  = (e == 2) ? h : (0.5f * h);        // e==3: unused
        const float tadd = (e == 3) ? h : ((e == 0) ? 0.f : (0.5f * h));
        const float t = t0 + ((e4 >> 2) ? h : 0.f) + tadd;
        const float tbx = t * (wt0.x + wt1.x + wt2.x) + bv.x;
        const float tby = t * (wt0.y + wt1.y + wt2.y) + bv.y;

#pragma unroll
        for (int bb = 0; bb < 3; bb++) {
            const int r0 = (rh * 3 + bb) * 16;
            f32x4 acc0 = {0.f, 0.f, 0.f, 0.f};
            f32x4 acc1 = {0.f, 0.f, 0.f, 0.f};
#pragma unroll
            for (int c = 0; c < 6; c++) {
                const int zr = r0 + ml + (c >> 1);   // data row r0+ml-1+kw -> z row +1
                const bf16x8 a =
                    *(const bf16x8*)&zin[zr * ZST + ((c & 1) * 32) + g * 8];
                acc0 = __builtin_amdgcn_mfma_f32_16x16x32_bf16(a, Bf[c][0], acc0, 0, 0, 0);
                acc1 = __builtin_amdgcn_mfma_f32_16x16x32_bf16(a, Bf[c][1], acc1, 0, 0, 0);
            }
#pragma unroll
            for (int i = 0; i < 4; i++) {
                const int r = r0 + g * 4 + i;
                float k0 = acc0[i] + tbx;
                float k1 = acc1[i] + tby;
                if (edge) {
                    const int l = l0 - HALO + r;
                    if (l == 0)      { k0 -= t * wt0.x; k1 -= t * wt0.y; }
                    if (l == LL - 1) { k0 -= t * wt2.x; k1 -= t * wt2.y; }
                }
                k0 = fmaxf(k0, 0.f);
                k1 = fmaxf(k1, 0.f);
                const float2 y2 = yR[bb][i];
                if (e == 0) {
                    aR[bb][i].x = y2.x + cacc * k0;
                    aR[bb][i].y = y2.y + cacc * k1;
                } else {
                    aR[bb][i].x += cacc * k0;
                    aR[bb][i].y += cacc * k1;
                }
                if (e4 == 3)   // step-1 done: new y base = aR, stays in regs
                    yR[bb][i] = aR[bb][i];
                if (e4 != 7) {
                    float u0 = 0.f, u1 = 0.f;
                    if (r >= rmin && r < rmax) {     // seq-boundary rows stay 0
                        if (e == 3) { u0 = yR[bb][i].x; u1 = yR[bb][i].y; }
                        else        { u0 = y2.x + cuu * k0; u1 = y2.y + cuu * k1; }
                    }
                    *(unsigned*)&zout[(r + 1) * ZST + co] = cvtpk(u0, u1);
                }
            }
        }
        if (e4 != 7) __syncthreads();
    }

    // ---- store central rows (r in [HALO, HALO+TILE) and < rmax) ----
#pragma unroll
    for (int bb = 0; bb < 3; bb++) {
        const int r0 = (rh * 3 + bb) * 16;
#pragma unroll
        for (int i = 0; i < 4; i++) {
            const int r = r0 + g * 4 + i;
            if (r >= HALO && r < HALO + TILE && r < rmax) {
                const int l = l0 - HALO + r;
                *(float2*)(y_out + ((size_t)b * LL + l) * CC + co) = aR[bb][i];
            }
        }
    }
}

extern "C" void kernel_launch(void* const* d_in, const int* in_sizes, int n_in,
                              void* d_out, int out_size, void* d_ws, size_t ws_size,
                              hipStream_t stream) {
    const float* x = (const float*)d_in[0];
    const float* w = (const float*)d_in[1];
    const float* bias = (const float*)d_in[2];
    float* out = (float*)d_out;
    float* P0 = (float*)d_ws;   // 32*8192*64*4 = 67.1 MB scratch
    const float h = 1.0f / 8.0f;

    dim3 grid(NBLK, BB), block(THREADS);
    for (int s = 0; s < 4; s++) {   // each kernel = 2 fused RK4 steps
        const float* yin = (s == 0) ? x : ((s & 1) ? P0 : out);
        float* yout = (s & 1) ? out : P0;   // s=3 (odd) writes `out`
        step_kernel<<<grid, block, 0, stream>>>(yin, yout, w, bias, (2 * s) * h, h);
    }
}